// Round 8
// baseline (62.744 us; speedup 1.0000x reference)
//
#include <hip/hip_runtime.h>

#define D1 8
#define RANK 8
#define ROWS 6

typedef float v2f __attribute__((ext_vector_type(2)));
typedef float v4f __attribute__((ext_vector_type(4)));

// D (v2f) += broadcast(A.lo) * B
#define PK_FMA_LO(D, A, B) \
  asm("v_pk_fma_f32 %0, %1, %2, %0 op_sel:[0,0,0] op_sel_hi:[0,1,1]" : "+v"(D) : "v"(A), "v"(B))
// D (v2f) += broadcast(A.hi) * B
#define PK_FMA_HI(D, A, B) \
  asm("v_pk_fma_f32 %0, %1, %2, %0 op_sel:[1,0,0] op_sel_hi:[1,1,1]" : "+v"(D) : "v"(A), "v"(B))
// D += A * B element-wise
#define PK_FMA(D, A, B) \
  asm("v_pk_fma_f32 %0, %1, %2, %0" : "+v"(D) : "v"(A), "v"(B))
// D *= A element-wise
#define PK_MUL(D, A) \
  asm("v_pk_mul_f32 %0, %0, %1" : "+v"(D) : "v"(A))

// one 4-r half-block against an 8x v4f coefficient buffer
#define HALF_BLOCK_PK(ACC2, SRC2, BUF, RPOFF)                                        \
    _Pragma("unroll")                                                                \
    for (int rr = 0; rr < 4; ++rr) {                                                 \
        _Pragma("unroll")                                                            \
        for (int k = 0; k < ROWS; ++k) {                                             \
            if ((rr & 1) == 0) {                                                     \
                PK_FMA_LO(ACC2[k][0], SRC2[k][(RPOFF) + (rr >> 1)], BUF[2*rr].lo);   \
                PK_FMA_LO(ACC2[k][1], SRC2[k][(RPOFF) + (rr >> 1)], BUF[2*rr].hi);   \
                PK_FMA_LO(ACC2[k][2], SRC2[k][(RPOFF) + (rr >> 1)], BUF[2*rr+1].lo); \
                PK_FMA_LO(ACC2[k][3], SRC2[k][(RPOFF) + (rr >> 1)], BUF[2*rr+1].hi); \
            } else {                                                                 \
                PK_FMA_HI(ACC2[k][0], SRC2[k][(RPOFF) + (rr >> 1)], BUF[2*rr].lo);   \
                PK_FMA_HI(ACC2[k][1], SRC2[k][(RPOFF) + (rr >> 1)], BUF[2*rr].hi);   \
                PK_FMA_HI(ACC2[k][2], SRC2[k][(RPOFF) + (rr >> 1)], BUF[2*rr+1].lo); \
                PK_FMA_HI(ACC2[k][3], SRC2[k][(RPOFF) + (rr >> 1)], BUF[2*rr+1].hi); \
            }                                                                        \
        }                                                                            \
    }

__global__ __launch_bounds__(256, 2) void tt_poly_kernel(
    const float* __restrict__ X,
    const float* __restrict__ G0,   // [d1, r]
    const float* __restrict__ G1,   // [r, d1, s]
    const float* __restrict__ G2,   // [r, d1, s]
    const float* __restrict__ G3,   // [t, d1]
    float* __restrict__ out,
    int B, int S)
{
    __shared__ v4f sG0v[16];        // [d][r]
    __shared__ v4f sG1Tv[128];      // [d][r][s]
    __shared__ v4f sG2Tv[128];
    __shared__ v4f sG3Tv[16];       // [d][t]

    const int tid = threadIdx.x;
    if (tid < 128) {
        v4f v = reinterpret_cast<const v4f*>(G1)[tid];
        int r = tid >> 4, d = (tid >> 1) & 7, h = tid & 1;
        sG1Tv[d * 16 + r * 2 + h] = v;
    } else {
        int i = tid - 128;
        v4f v = reinterpret_cast<const v4f*>(G2)[i];
        int r = i >> 4, d = (i >> 1) & 7, h = i & 1;
        sG2Tv[d * 16 + r * 2 + h] = v;
    }
    if (tid < 16)
        sG0v[tid] = reinterpret_cast<const v4f*>(G0)[tid];
    else if (tid < 80) {
        int i = tid - 16;                 // i = t*8 + d
        reinterpret_cast<float*>(sG3Tv)[(i & 7) * RANK + (i >> 3)] = G3[i];
    }
    __syncthreads();

    const int gid = blockIdx.x * blockDim.x + tid;

    v4f x[ROWS];
    #pragma unroll
    for (int k = 0; k < ROWS; ++k) {
        int bb = gid + k * S;
        if (bb < B) x[k] = reinterpret_cast<const v4f*>(X)[bb];
        else        x[k] = (v4f){0.f, 0.f, 0.f, 0.f};
    }

    v2f a2[ROWS][4];
    v2f b2[ROWS][4];
    v2f xpd[ROWS];

    // ---- stage 1: a[k][r] = sum_d x0^d G0[d][r] ----
    {
        v2f xd[ROWS];
        #pragma unroll
        for (int k = 0; k < ROWS; ++k) {
            xpd[k] = (v2f){1.f, 1.f};
            xd[k]  = (v2f){x[k].x, x[k].x};
            #pragma unroll
            for (int j = 0; j < 4; ++j) a2[k][j] = (v2f){0.f, 0.f};
        }
        #pragma unroll
        for (int d = 0; d < D1; ++d) {
            v4f r0 = sG0v[2 * d], r1 = sG0v[2 * d + 1];
            #pragma unroll
            for (int k = 0; k < ROWS; ++k) {
                PK_FMA(a2[k][0], xpd[k], r0.lo);
                PK_FMA(a2[k][1], xpd[k], r0.hi);
                PK_FMA(a2[k][2], xpd[k], r1.lo);
                PK_FMA(a2[k][3], xpd[k], r1.hi);
                PK_MUL(xpd[k], xd[k]);
            }
        }
    }

    // ---- stage 2: b = contract(a, G1, x1) ----
    {
        v2f xyd[ROWS];
        #pragma unroll
        for (int k = 0; k < ROWS; ++k) {
            xyd[k] = (v2f){x[k].y, x[k].y};
            #pragma unroll
            for (int j = 0; j < 4; ++j) b2[k][j] = (v2f){0.f, 0.f};
        }
        const v4f* g = sG1Tv;
        v4f buf[8];
        #pragma unroll 1
        for (int t = 0; t < D1; ++t) {
            #pragma unroll
            for (int j = 0; j < 8; ++j) buf[j] = g[t * 16 + j];
            HALF_BLOCK_PK(b2, a2, buf, 0)
            #pragma unroll
            for (int j = 0; j < 8; ++j) buf[j] = g[t * 16 + 8 + j];
            HALF_BLOCK_PK(b2, a2, buf, 2)
            if (t < D1 - 1) {
                #pragma unroll
                for (int k = 0; k < ROWS; ++k)
                    #pragma unroll
                    for (int j = 0; j < 4; ++j) PK_MUL(a2[k][j], xyd[k]);
            }
        }
    }

    // ---- stage 3: a = contract(b, G2, x2) ----
    {
        v2f xzd[ROWS];
        #pragma unroll
        for (int k = 0; k < ROWS; ++k) {
            xzd[k] = (v2f){x[k].z, x[k].z};
            #pragma unroll
            for (int j = 0; j < 4; ++j) a2[k][j] = (v2f){0.f, 0.f};
        }
        const v4f* g = sG2Tv;
        v4f buf[8];
        #pragma unroll 1
        for (int t = 0; t < D1; ++t) {
            #pragma unroll
            for (int j = 0; j < 8; ++j) buf[j] = g[t * 16 + j];
            HALF_BLOCK_PK(a2, b2, buf, 0)
            #pragma unroll
            for (int j = 0; j < 8; ++j) buf[j] = g[t * 16 + 8 + j];
            HALF_BLOCK_PK(a2, b2, buf, 2)
            if (t < D1 - 1) {
                #pragma unroll
                for (int k = 0; k < ROWS; ++k)
                    #pragma unroll
                    for (int j = 0; j < 4; ++j) PK_MUL(b2[k][j], xzd[k]);
            }
        }
    }

    // ---- stage 4: res[k] = sum_d x3^d (sum_t a[k][t] G3[t][d]) ----
    v2f res2[ROWS];
    {
        v2f xwd[ROWS];
        #pragma unroll
        for (int k = 0; k < ROWS; ++k) {
            res2[k] = (v2f){0.f, 0.f};
            xpd[k]  = (v2f){1.f, 1.f};
            xwd[k]  = (v2f){x[k].w, x[k].w};
        }
        #pragma unroll
        for (int d = 0; d < D1; ++d) {
            v4f r0 = sG3Tv[2 * d], r1 = sG3Tv[2 * d + 1];
            #pragma unroll
            for (int k = 0; k < ROWS; ++k) {
                v2f e = a2[k][0];
                PK_MUL(e, r0.lo);
                PK_FMA(e, a2[k][1], r0.hi);
                PK_FMA(e, a2[k][2], r1.lo);
                PK_FMA(e, a2[k][3], r1.hi);
                PK_FMA(res2[k], e, xpd[k]);
                PK_MUL(xpd[k], xwd[k]);
            }
        }
    }

    #pragma unroll
    for (int k = 0; k < ROWS; ++k) {
        int bb = gid + k * S;
        if (bb < B) out[bb] = res2[k].x + res2[k].y;
    }
}

extern "C" void kernel_launch(void* const* d_in, const int* in_sizes, int n_in,
                              void* d_out, int out_size, void* d_ws, size_t ws_size,
                              hipStream_t stream) {
    const float* X  = (const float*)d_in[0];
    const float* G0 = (const float*)d_in[1];
    const float* G1 = (const float*)d_in[2];
    const float* G2 = (const float*)d_in[3];
    const float* G3 = (const float*)d_in[4];
    float* out = (float*)d_out;

    int B = in_sizes[0] / 4;   // X is [B,4]
    int block = 256;
    int grid = (B + block * ROWS - 1) / (block * ROWS);
    int S = grid * block;
    tt_poly_kernel<<<grid, block, 0, stream>>>(X, G0, G1, G2, G3, out, B, S);
}

// Round 10
// 39.357 us; speedup vs baseline: 1.5942x; 1.5942x over previous
//
#include <hip/hip_runtime.h>
#include <hip/hip_bf16.h>

#define D1 8
#define RANK 8

typedef float f32x4 __attribute__((ext_vector_type(4)));
typedef short bf16x8 __attribute__((ext_vector_type(8)));

// pack 2 fp32 -> 2 bf16 (RNE): bits[15:0]=bf16(lo), bits[31:16]=bf16(hi)
__device__ inline unsigned cvt_pk_bf16(float lo, float hi) {
    unsigned r;
    asm("v_cvt_pk_bf16_f32 %0, %1, %2" : "=v"(r) : "v"(lo), "v"(hi));
    return r;
}

union FragU { unsigned u[4]; bf16x8 v; };

__device__ inline bf16x8 pack8(const float f[8]) {
    FragU x;
    x.u[0] = cvt_pk_bf16(f[0], f[1]);
    x.u[1] = cvt_pk_bf16(f[2], f[3]);
    x.u[2] = cvt_pk_bf16(f[4], f[5]);
    x.u[3] = cvt_pk_bf16(f[6], f[7]);
    return x.v;
}

__device__ inline bf16x8 splat8(float v) {
    FragU x;
    unsigned p = cvt_pk_bf16(v, v);
    x.u[0] = p; x.u[1] = p; x.u[2] = p; x.u[3] = p;
    return x.v;
}

// B-operand fragments for one 64x8 G matrix (flat [k][s], k=r*8+d), exact
// bf16 hi+lo split. Slot (grp,e) of block q holds G[32q+8grp+e][col] (cols>=8 zero).
__device__ inline void build_b(const float* __restrict__ G, int col, int grp,
                               bf16x8* Bh, bf16x8* Bl) {
    #pragma unroll
    for (int q = 0; q < 2; ++q) {
        FragU hi, lo;
        #pragma unroll
        for (int pr = 0; pr < 4; ++pr) {
            float v0 = 0.f, v1 = 0.f;
            if (col < 8) {
                v0 = G[(32*q + 8*grp + 2*pr    ) * 8 + col];
                v1 = G[(32*q + 8*grp + 2*pr + 1) * 8 + col];
            }
            float h0 = __bfloat162float(__float2bfloat16(v0));
            float h1 = __bfloat162float(__float2bfloat16(v1));
            hi.u[pr] = cvt_pk_bf16(h0, h1);
            lo.u[pr] = cvt_pk_bf16(v0 - h0, v1 - h1);
        }
        Bh[q] = hi.v;
        Bl[q] = lo.v;
    }
}

#define POWERS(p, xx)                                              \
    p[0] = 1.f;  p[1] = (xx);      p[2] = p[1]*p[1];               \
    p[3] = p[2]*p[1]; p[4] = p[2]*p[2]; p[5] = p[4]*p[1];          \
    p[6] = p[4]*p[2]; p[7] = p[4]*p[3];

__global__ __launch_bounds__(256) void tt_poly_kernel(
    const float* __restrict__ X,
    const float* __restrict__ G0,   // [d1][r]
    const float* __restrict__ G1,   // [r][d1][s] -> flat [64][8]
    const float* __restrict__ G2,   // [r][d1][s] -> flat [64][8]
    const float* __restrict__ G3,   // [t][d1]
    float* __restrict__ out,
    int B, int NW)                  // NW = total waves in grid
{
    __shared__ float L[4][RANK][68];   // per-wave [s_or_r][sample] scratch

    const int tid  = threadIdx.x;
    const int w    = tid >> 6;
    const int lane = tid & 63;
    const int col  = lane & 15;
    const int grp  = lane >> 4;

    // ---- MFMA C-layout self-calibration (assumption-free routing) ----
    // probe1: A slots = row-label(l&15), B = ones  -> C slot = 32*sampleLabel
    // probe2: A = ones, B slots = col-label(l&15)  -> C slot = 32*sLabel
    int rowLbl[4], colLbl[4];
    {
        bf16x8 ones = splat8(1.f);
        bf16x8 lbl  = splat8((float)col);
        f32x4 pr = {0.f, 0.f, 0.f, 0.f};
        f32x4 pc = {0.f, 0.f, 0.f, 0.f};
        pr = __builtin_amdgcn_mfma_f32_16x16x32_bf16(lbl, ones, pr, 0, 0, 0);
        pc = __builtin_amdgcn_mfma_f32_16x16x32_bf16(ones, lbl, pc, 0, 0, 0);
        #pragma unroll
        for (int j = 0; j < 4; ++j) {
            rowLbl[j] = (int)(pr[j] * 0.03125f + 0.5f);
            colLbl[j] = (int)(pc[j] * 0.03125f + 0.5f);
        }
    }

    bf16x8 B1h[2], B1l[2], B2h[2], B2l[2];
    build_b(G1, col, grp, B1h, B1l);
    build_b(G2, col, grp, B2h, B2l);

    float* Lw = &L[w][0][0];
    const int gw = blockIdx.x * 4 + w;

    #pragma unroll 1
    for (int it = 0; it < 4; ++it) {
        const int b = (it * NW + gw) * 64 + lane;
        float4 xv = make_float4(0.f, 0.f, 0.f, 0.f);
        if (b < B) xv = reinterpret_cast<const float4*>(X)[b];

        // ---- stage 1 (fp32 VALU): t[r] = sum_d x0^d G0[d][r] ----
        {
            float p[8];
            POWERS(p, xv.x)
            #pragma unroll
            for (int r = 0; r < 8; ++r) {
                float t = 0.f;
                #pragma unroll
                for (int d = 0; d < 8; ++d)
                    t = fmaf(p[d], G0[d*8 + r], t);
                Lw[r*68 + lane] = t;               // [r][sample]
            }
        }

        // ---- stages 2,3 via MFMA, 4 groups of 16 samples ----
        #pragma unroll 1
        for (int g4 = 0; g4 < 4; ++g4) {
            // stage 2: t1 = (t (x) P1) @ G1
            {
                float x1 = __shfl(xv.y, g4*16 + col, 64);
                float p[8];
                POWERS(p, x1)
                float ta = Lw[grp*68     + g4*16 + col];   // t[grp]
                float tb = Lw[(grp+4)*68 + g4*16 + col];   // t[grp+4]
                float f0[8], f1[8];
                #pragma unroll
                for (int e = 0; e < 8; ++e) { f0[e] = ta*p[e]; f1[e] = tb*p[e]; }
                bf16x8 a0 = pack8(f0), a1 = pack8(f1);
                f32x4 acc = {0.f, 0.f, 0.f, 0.f};
                acc = __builtin_amdgcn_mfma_f32_16x16x32_bf16(a0, B1h[0], acc, 0, 0, 0);
                acc = __builtin_amdgcn_mfma_f32_16x16x32_bf16(a0, B1l[0], acc, 0, 0, 0);
                acc = __builtin_amdgcn_mfma_f32_16x16x32_bf16(a1, B1h[1], acc, 0, 0, 0);
                acc = __builtin_amdgcn_mfma_f32_16x16x32_bf16(a1, B1l[1], acc, 0, 0, 0);
                #pragma unroll
                for (int j = 0; j < 4; ++j)
                    if (colLbl[j] < 8)
                        Lw[colLbl[j]*68 + g4*16 + rowLbl[j]] = acc[j];
            }
            // stage 3: t2 = (t1 (x) P2) @ G2
            {
                float x2 = __shfl(xv.z, g4*16 + col, 64);
                float p[8];
                POWERS(p, x2)
                float ta = Lw[grp*68     + g4*16 + col];
                float tb = Lw[(grp+4)*68 + g4*16 + col];
                float f0[8], f1[8];
                #pragma unroll
                for (int e = 0; e < 8; ++e) { f0[e] = ta*p[e]; f1[e] = tb*p[e]; }
                bf16x8 a0 = pack8(f0), a1 = pack8(f1);
                f32x4 acc = {0.f, 0.f, 0.f, 0.f};
                acc = __builtin_amdgcn_mfma_f32_16x16x32_bf16(a0, B2h[0], acc, 0, 0, 0);
                acc = __builtin_amdgcn_mfma_f32_16x16x32_bf16(a0, B2l[0], acc, 0, 0, 0);
                acc = __builtin_amdgcn_mfma_f32_16x16x32_bf16(a1, B2h[1], acc, 0, 0, 0);
                acc = __builtin_amdgcn_mfma_f32_16x16x32_bf16(a1, B2l[1], acc, 0, 0, 0);
                #pragma unroll
                for (int j = 0; j < 4; ++j)
                    if (colLbl[j] < 8)
                        Lw[colLbl[j]*68 + g4*16 + rowLbl[j]] = acc[j];
            }
        }

        // ---- stage 4 (fp32 VALU): res = sum_t t2[t] * (G3[t]·P3) ----
        {
            float p[8];
            POWERS(p, xv.w)
            float res = 0.f;
            #pragma unroll
            for (int t = 0; t < 8; ++t) {
                float wt = 0.f;
                #pragma unroll
                for (int d = 0; d < 8; ++d)
                    wt = fmaf(p[d], G3[t*8 + d], wt);
                res = fmaf(Lw[t*68 + lane], wt, res);
            }
            if (b < B) out[b] = res;
        }
    }
}

extern "C" void kernel_launch(void* const* d_in, const int* in_sizes, int n_in,
                              void* d_out, int out_size, void* d_ws, size_t ws_size,
                              hipStream_t stream) {
    const float* X  = (const float*)d_in[0];
    const float* G0 = (const float*)d_in[1];
    const float* G1 = (const float*)d_in[2];
    const float* G2 = (const float*)d_in[3];
    const float* G3 = (const float*)d_in[4];
    float* out = (float*)d_out;

    int B = in_sizes[0] / 4;                       // X is [B,4]
    int block = 256;
    int grid = (B + block * 4 - 1) / (block * 4);  // 4 samples/thread over 4 iters
    int NW = grid * 4;                             // total waves
    tt_poly_kernel<<<grid, block, 0, stream>>>(X, G0, G1, G2, G3, out, B, NW);
}